// Round 8
// baseline (31816.840 us; speedup 1.0000x reference)
//
#include <hip/hip_runtime.h>
#include <hip/hip_bf16.h>
#include <cstddef>

#define B_ 128
#define T_ 256
#define H_ 512
#define H4_ 2048

__device__ __forceinline__ float rcp_f(float x) { return __builtin_amdgcn_rcpf(x); }
__device__ __forceinline__ float sigf(float x) { return rcp_f(1.0f + __expf(-x)); }
__device__ __forceinline__ float tanh_f(float x) {
  float p = __expf(x + x);
  return fmaf(-2.0f, rcp_f(1.0f + p), 1.0f);
}
__device__ __forceinline__ float4 ld4(const float* p) { return *reinterpret_cast<const float4*>(p); }
__device__ __forceinline__ void st4(float* p, float4 v) { *reinterpret_cast<float4*>(p) = v; }
__device__ __forceinline__ void fma4(float4& a, float s, float4 w) {
  a.x = fmaf(s, w.x, a.x); a.y = fmaf(s, w.y, a.y);
  a.z = fmaf(s, w.z, a.z); a.w = fmaf(s, w.w, a.w);
}

// ---- agent-scope (device-coherent, L1/L2-bypassing) accessors ----
__device__ __forceinline__ float ald1(const float* p) {
  return __hip_atomic_load(p, __ATOMIC_RELAXED, __HIP_MEMORY_SCOPE_AGENT);
}
__device__ __forceinline__ void ast1(float* p, float v) {
  __hip_atomic_store(p, v, __ATOMIC_RELAXED, __HIP_MEMORY_SCOPE_AGENT);
}
__device__ __forceinline__ float2 ald2(const float* p) {
  unsigned long long v = __hip_atomic_load((const unsigned long long*)p,
                                           __ATOMIC_RELAXED, __HIP_MEMORY_SCOPE_AGENT);
  union { unsigned long long u; float2 f; } c; c.u = v; return c.f;
}

// fp16 helpers
union H4u { ushort4 u; _Float16 h[4]; };
union H8u { int4 v; _Float16 h[8]; };
__device__ __forceinline__ void sth4(_Float16* p, float4 v) {
  H4u c;
  c.h[0] = (_Float16)v.x; c.h[1] = (_Float16)v.y;
  c.h[2] = (_Float16)v.z; c.h[3] = (_Float16)v.w;
  *reinterpret_cast<ushort4*>(p) = c.u;
}

// ---------------- workspace layout (float offsets) ----------------
#define W1EH_OFF  0ull           // 8388608 floats (16.8M halfs: w1e fp16 [32768][512])
#define WPACK_OFF 8388608ull     // 1572864: Wpack[32 gblk][768 k][64 c']  c'=j*4+gate
#define W2H_OFF   9961472ull     // 131072 floats (262144 halfs: W2h [512][512])
#define HROW_OFF  10092544ull    // 131072: hrow[2][128 b][512]
#define EROW_OFF  10223616ull    // 32768:  erow[128 b][256 t]
#define D2_OFF    10256384ull    // 512:    d2[2][128 b][2]
#define CNT_OFF   10256896ull    // 1024 uints

// ---------------- w1e = enc[32768,512] @ W1[512,512], output fp16 ----------------
__global__ __launch_bounds__(256) void w1e_kernel(const float* __restrict__ A,
                                                  const float* __restrict__ Bw,
                                                  _Float16* __restrict__ C) {
  __shared__ float As[32][68];
  __shared__ float Bs[32][68];
  const int i0 = blockIdx.x * 64;
  const int j0 = blockIdx.y * 64;
  const int tx = threadIdx.x & 15, ty = threadIdx.x >> 4;
  float4 acc0 = make_float4(0,0,0,0), acc1 = acc0, acc2 = acc0, acc3 = acc0;
  for (int k0 = 0; k0 < H_; k0 += 32) {
#pragma unroll
    for (int q = 0; q < 2; q++) {
      int idx = q * 256 + threadIdx.x;
      int ai = idx >> 3, ak = (idx & 7) << 2;
      float4 av = ld4(A + (size_t)(i0 + ai) * H_ + k0 + ak);
      As[ak][ai] = av.x; As[ak + 1][ai] = av.y; As[ak + 2][ai] = av.z; As[ak + 3][ai] = av.w;
      int bk = idx >> 4, bj = (idx & 15) << 2;
      st4(&Bs[bk][bj], ld4(Bw + (size_t)(k0 + bk) * H_ + j0 + bj));
    }
    __syncthreads();
#pragma unroll
    for (int kk = 0; kk < 32; kk++) {
      float4 a = ld4(&As[kk][ty << 2]);
      float4 bv = ld4(&Bs[kk][tx << 2]);
      fma4(acc0, a.x, bv); fma4(acc1, a.y, bv); fma4(acc2, a.z, bv); fma4(acc3, a.w, bv);
    }
    __syncthreads();
  }
  size_t base = (size_t)(i0 + (ty << 2)) * H_ + j0 + (tx << 2);
  sth4(&C[base], acc0); sth4(&C[base + H_], acc1);
  sth4(&C[base + 2 * H_], acc2); sth4(&C[base + 3 * H_], acc3);
}

// -------- pack: Wpack[gblk][k][c'] (c'=j*4+gate), W2 fp16, zero counters --------
__global__ __launch_bounds__(256) void pack_kernel(const float* __restrict__ Wk,
                                                   const float* __restrict__ Wr,
                                                   const float* __restrict__ W2,
                                                   float* __restrict__ Wpack,
                                                   _Float16* __restrict__ W2h,
                                                   unsigned* __restrict__ cnt) {
  const int g = blockIdx.x, tid = threadIdx.x;
  const int gblk = g >> 3, slice = g & 7;   // k-slice of 96
#pragma unroll
  for (int it = 0; it < 24; ++it) {
    int idx = it * 256 + tid;               // 0..6143 = 96 k x 64 c'
    int kk = idx >> 6, c = idx & 63;
    int k = slice * 96 + kk;
    int col = (c & 3) * 512 + gblk * 16 + (c >> 2);   // gate*512 + h-col
    float v = (k < 256) ? Wk[(size_t)k * H4_ + col] : Wr[(size_t)(k - 256) * H4_ + col];
    Wpack[((size_t)gblk * 768 + k) * 64 + c] = v;
  }
#pragma unroll
  for (int it = 0; it < 4; ++it) {
    int idx = it * 65536 + g * 256 + tid;
    W2h[idx] = (_Float16)W2[idx];
  }
  if (g == 0) {
#pragma unroll
    for (int i = 0; i < 4; ++i) cnt[i * 256 + tid] = 0u;
  }
}

// ---------------- low-contention two-level grid barrier (no fences) ----------------
__device__ __forceinline__ void gridbar(unsigned* cnt, unsigned& phase, int tid, int wg) {
  asm volatile("s_waitcnt vmcnt(0)" ::: "memory");  // every wave: own stores at LLC
  __syncthreads();
  if (tid == 0) {
    unsigned r1 = __hip_atomic_fetch_add(&cnt[(wg & 31) * 16], 1u,
                                         __ATOMIC_RELAXED, __HIP_MEMORY_SCOPE_AGENT);
    if (r1 == phase * 8u + 7u) {
      unsigned r2 = __hip_atomic_fetch_add(&cnt[512], 1u,
                                           __ATOMIC_RELAXED, __HIP_MEMORY_SCOPE_AGENT);
      if (r2 == phase * 32u + 31u) {
#pragma unroll
        for (int i = 0; i < 8; ++i)
          __hip_atomic_store(&cnt[768 + i * 16], phase + 1u,
                             __ATOMIC_RELAXED, __HIP_MEMORY_SCOPE_AGENT);
      }
    }
    const unsigned* rel = &cnt[768 + (wg >> 5) * 16];
    while (__hip_atomic_load(rel, __ATOMIC_RELAXED, __HIP_MEMORY_SCOPE_AGENT) <= phase)
      __builtin_amdgcn_s_sleep(2);
  }
  __syncthreads();
  ++phase;
}

// ---------------- persistent decoder: 256 WGs x 1024 thr, 1 WG/CU ----------------
// Gates role: WG = (bblk = g>>5: 16 rows) x (cblk = g&31: 64 packed cols)
// Score role: WG = (sb = g>>1) x (t-half = g&1)  [unchanged from r7]
__global__ __launch_bounds__(1024, 4) void decoder_persistent(
    const _Float16* __restrict__ w1eh, const float* __restrict__ Wpack,
    const _Float16* __restrict__ W2h, const float* __restrict__ Vv,
    const float* __restrict__ bias, const float* __restrict__ h0,
    const float* __restrict__ c0,
    float* __restrict__ hrowB,  // [2][128][512]
    float* __restrict__ erow,   // [128][256]
    float* __restrict__ d2,     // [2][128][2]
    unsigned* __restrict__ cnt,
    float* __restrict__ out) {
  // 84KB LDS: forces 1 WG/CU -> all 256 WGs co-resident (barrier deadlock-free)
  __shared__ float smem[21504];
  float* zred    = smem;                 // gates [8ks][16b][66]; score: w2dzred[16][512]+dred@8192
  float* zfin    = smem + 8448;          // gates [16][68]; score: hrow_lds@8448, w2d_lds@8960
  float* stage_e = smem + 9536;          // [16][260] fp32
  _Float16* stageh = (_Float16*)(smem + 13696);  // [16][520] fp16
  float* c_lds   = smem + 17856;         // [16][16]
  float* bias64  = smem + 18112;         // [64]
  float* d_lds   = smem + 18176;         // [16]
  float* dred    = smem + 8192;          // [16] (inside zred region, after w2dzred)
  float* hrow_lds= smem + 8448;          // [512] (score phase)
  float* w2d_lds = smem + 8960;          // [512] (score phase)

  const int g = blockIdx.x;
  const int tid = threadIdx.x;
  // gates roles
  const int bblk = g >> 5, cblk = g & 31;
  const int b0 = bblk << 4;              // first batch row of this WG's gate tile
  const int ks = __builtin_amdgcn_readfirstlane(tid >> 7);  // 0..7 k-split
  const int br = (tid >> 3) & 15;        // 0..15 row within tile (FMA role)
  const int cg = tid & 7;                // 0..7 col-group (8 cols each)
  // score roles
  const int wv = tid >> 6, ln = tid & 63;
  const int sb = g >> 1;
  const int t0 = (g & 1) << 7;
  unsigned phase = 0;
  float epv[8];

  // ---- init ----
  if (tid < 64) bias64[tid] = bias[(tid & 3) * 512 + (cblk << 4) + (tid >> 2)];
  if (tid < 256) {
    int b3 = tid >> 4, j = tid & 15;
    int bg = b0 + b3, jg = (cblk << 4) + j;
    c_lds[(b3 << 4) + j] = c0[(size_t)bg * H_ + jg];
    ast1(hrowB + 65536 + (size_t)bg * 512 + jg, h0[(size_t)bg * H_ + jg]);
    if (g == 0) ast1(d2 + 256 + tid, 0.5f);   // d(-1): pair sums to 1
  }
  if (g < 128 && tid < 256) ast1(erow + g * 256 + tid, 1.0f);   // e(-1)=1
  gridbar(cnt, phase, tid, g);

  const float4 v0 = ld4(Vv + (ln << 3));
  const float4 v1 = ld4(Vv + (ln << 3) + 4);
  const _Float16* rowb = w1eh + (((size_t)sb * 256 + t0 + (wv << 3)) << 9) + (ln << 3);
  const float* WpG = Wpack + (size_t)cblk * 768 * 64;

  for (int s = 0; s < 256; ++s) {
    const float* hin = hrowB + ((s + 1) & 1) * 65536;
    float* hout = hrowB + (s & 1) * 65536;
    const float* dPrev = d2 + ((s + 1) & 1) * 256;
    float* dCur = d2 + (s & 1) * 256;

    // ---- prefetch score-phase w1e rows (step-invariant addresses) ----
    H8u raws[8];
#pragma unroll
    for (int r = 0; r < 8; ++r)
      raws[r].v = *reinterpret_cast<const int4*>(rowb + ((size_t)r << 9));

    // ================= phase 1: gates =================
    // stage e (fp32) + h (fp16) + d for this WG's 16 rows into LDS
    {
      int row = tid >> 6;
      int ec = (tid & 63) << 2;
      float2 ea = ald2(erow + (size_t)(b0 + row) * 256 + ec);
      float2 eb = ald2(erow + (size_t)(b0 + row) * 256 + ec + 2);
      st4(&stage_e[row * 260 + ec], make_float4(ea.x, ea.y, eb.x, eb.y));
      int hc = (tid & 63) << 3;
      const float* hp = hin + (size_t)(b0 + row) * 512 + hc;
      float2 h0v = ald2(hp), h1v = ald2(hp + 2), h2v = ald2(hp + 4), h3v = ald2(hp + 6);
      sth4(&stageh[row * 520 + hc], make_float4(h0v.x, h0v.y, h1v.x, h1v.y));
      sth4(&stageh[row * 520 + hc + 4], make_float4(h2v.x, h2v.y, h3v.x, h3v.y));
      if (tid < 16) {
        float2 dd = ald2(dPrev + (b0 + tid) * 2);
        d_lds[tid] = dd.x + dd.y;
      }
    }
    __syncthreads();
    // FMA: thread (ks, br, cg): 8 cols, e-slice K=32, h-slice K=64
    {
      float4 aE0 = make_float4(0,0,0,0), aE1 = aE0, aH0 = aE0, aH1 = aE0;
#pragma unroll
      for (int kk = 0; kk < 32; kk += 4) {
        float4 ev = ld4(&stage_e[br * 260 + (ks << 5) + kk]);
        const float* wp = WpG + (size_t)((ks << 5) + kk) * 64 + (cg << 3);
        float4 w00 = ld4(wp),       w01 = ld4(wp + 4);
        float4 w10 = ld4(wp + 64),  w11 = ld4(wp + 68);
        float4 w20 = ld4(wp + 128), w21 = ld4(wp + 132);
        float4 w30 = ld4(wp + 192), w31 = ld4(wp + 196);
        fma4(aE0, ev.x, w00); fma4(aE1, ev.x, w01);
        fma4(aE0, ev.y, w10); fma4(aE1, ev.y, w11);
        fma4(aE0, ev.z, w20); fma4(aE1, ev.z, w21);
        fma4(aE0, ev.w, w30); fma4(aE1, ev.w, w31);
      }
#pragma unroll 4
      for (int kk = 0; kk < 64; kk += 4) {
        H4u hv; hv.u = *reinterpret_cast<const ushort4*>(&stageh[br * 520 + (ks << 6) + kk]);
        const float* wp = WpG + (size_t)(256 + (ks << 6) + kk) * 64 + (cg << 3);
        float4 w00 = ld4(wp),       w01 = ld4(wp + 4);
        float4 w10 = ld4(wp + 64),  w11 = ld4(wp + 68);
        float4 w20 = ld4(wp + 128), w21 = ld4(wp + 132);
        float4 w30 = ld4(wp + 192), w31 = ld4(wp + 196);
        fma4(aH0, (float)hv.h[0], w00); fma4(aH1, (float)hv.h[0], w01);
        fma4(aH0, (float)hv.h[1], w10); fma4(aH1, (float)hv.h[1], w11);
        fma4(aH0, (float)hv.h[2], w20); fma4(aH1, (float)hv.h[2], w21);
        fma4(aH0, (float)hv.h[3], w30); fma4(aH1, (float)hv.h[3], w31);
      }
      float rd = rcp_f(d_lds[br]);
      float4 z0, z1;
      z0.x = fmaf(aE0.x, rd, aH0.x); z0.y = fmaf(aE0.y, rd, aH0.y);
      z0.z = fmaf(aE0.z, rd, aH0.z); z0.w = fmaf(aE0.w, rd, aH0.w);
      z1.x = fmaf(aE1.x, rd, aH1.x); z1.y = fmaf(aE1.y, rd, aH1.y);
      z1.z = fmaf(aE1.z, rd, aH1.z); z1.w = fmaf(aE1.w, rd, aH1.w);
      float* zr = &zred[((ks << 4) + br) * 66 + (cg << 3)];
      st4(zr, z0); st4(zr + 4, z1);
    }
    __syncthreads();
    {  // k-split reduce: 1024 thr = 16 b x 64 c
      int b2 = tid >> 6, c2 = tid & 63;
      float zs = bias64[c2];
#pragma unroll
      for (int k2 = 0; k2 < 8; ++k2) zs += zred[((k2 << 4) + b2) * 66 + c2];
      zfin[b2 * 68 + c2] = zs;
    }
    __syncthreads();
    if (tid < 256) {  // LSTM epilogue: 16 rows x 16 h-cols (c-state in LDS)
      int b3 = tid >> 4, j = tid & 15;
      float zi = zfin[b3 * 68 + (j << 2) + 0];
      float zf = zfin[b3 * 68 + (j << 2) + 1];
      float zg = zfin[b3 * 68 + (j << 2) + 2];
      float zo = zfin[b3 * 68 + (j << 2) + 3];
      float cv = c_lds[(b3 << 4) + j];
      float cn = sigf(zf) * cv + sigf(zi) * tanh_f(zg);
      float hn = sigf(zo) * tanh_f(cn);
      c_lds[(b3 << 4) + j] = cn;
      ast1(hout + (size_t)(b0 + b3) * 512 + (cblk << 4) + j, hn);
    }
    gridbar(cnt, phase, tid, g);

    // ================= phase 2: fused w2d + score (row sb) =================
    if (tid < 256) {
      float2 hv = ald2(hout + (size_t)sb * 512 + (tid << 1));
      hrow_lds[(tid << 1)] = hv.x; hrow_lds[(tid << 1) + 1] = hv.y;
    }
    __syncthreads();
    {
      const int c8 = ln << 3;
      const _Float16* wp = W2h + ((size_t)(wv << 5) << 9) + c8;
      const float* hb = hrow_lds + (wv << 5);
      float4 accL = make_float4(0,0,0,0), accH = accL;
#pragma unroll 4
      for (int k = 0; k < 32; ++k) {
        float hk = hb[k];
        H8u w; w.v = *reinterpret_cast<const int4*>(wp + ((size_t)k << 9));
        accL.x = fmaf(hk, (float)w.h[0], accL.x);
        accL.y = fmaf(hk, (float)w.h[1], accL.y);
        accL.z = fmaf(hk, (float)w.h[2], accL.z);
        accL.w = fmaf(hk, (float)w.h[3], accL.w);
        accH.x = fmaf(hk, (float)w.h[4], accH.x);
        accH.y = fmaf(hk, (float)w.h[5], accH.y);
        accH.z = fmaf(hk, (float)w.h[6], accH.z);
        accH.w = fmaf(hk, (float)w.h[7], accH.w);
      }
      st4(&zred[(wv << 9) + c8], accL);
      st4(&zred[(wv << 9) + c8 + 4], accH);
    }
    __syncthreads();
    if (tid < 512) {
      float s16 = 0.0f;
#pragma unroll
      for (int q = 0; q < 16; ++q) s16 += zred[(q << 9) + tid];
      w2d_lds[tid] = s16;
    }
    __syncthreads();
    {
      float4 u0 = ld4(w2d_lds + (ln << 3));
      float4 u1 = ld4(w2d_lds + (ln << 3) + 4);
      float2 ddp = ald2(dPrev + sb * 2);
      float rdp = rcp_f(ddp.x + ddp.y);
      float sc[8];
#pragma unroll
      for (int r = 0; r < 8; ++r) {
        float a;
        a = tanh_f((float)raws[r].h[0] + u0.x) * v0.x;
        a = fmaf(tanh_f((float)raws[r].h[1] + u0.y), v0.y, a);
        a = fmaf(tanh_f((float)raws[r].h[2] + u0.z), v0.z, a);
        a = fmaf(tanh_f((float)raws[r].h[3] + u0.w), v0.w, a);
        a = fmaf(tanh_f((float)raws[r].h[4] + u1.x), v1.x, a);
        a = fmaf(tanh_f((float)raws[r].h[5] + u1.y), v1.y, a);
        a = fmaf(tanh_f((float)raws[r].h[6] + u1.z), v1.z, a);
        a = fmaf(tanh_f((float)raws[r].h[7] + u1.w), v1.w, a);
#pragma unroll
        for (int m = 32; m > 0; m >>= 1) a += __shfl_xor(a, m, 64);
        sc[r] = a;
      }
      if (ln == 0) {
        float dacc = 0.0f;
#pragma unroll
        for (int r = 0; r < 8; ++r) {
          int t = t0 + (wv << 3) + r;
          if (s > 0) out[(size_t)sb * 65536 + (size_t)(s - 1) * 256 + t] = epv[r] * rdp;
          float ev = __expf(sc[r]);
          epv[r] = ev;
          ast1(erow + (size_t)sb * 256 + t, ev);
          dacc += ev;
        }
        dred[wv] = dacc;
      }
    }
    __syncthreads();
    if (tid == 0) {
      float sd = 0.0f;
#pragma unroll
      for (int k = 0; k < 16; ++k) sd += dred[k];
      ast1(dCur + sb * 2 + (g & 1), sd);
    }
    gridbar(cnt, phase, tid, g);
  }

  // ---- final: out row 255 (e of step 255 in regs; d(255) in buffer 1) ----
  {
    float2 ddf = ald2(d2 + 256 + sb * 2);
    float rdf = rcp_f(ddf.x + ddf.y);
    if (ln == 0) {
#pragma unroll
      for (int r = 0; r < 8; ++r) {
        int t = t0 + (wv << 3) + r;
        out[(size_t)sb * 65536 + 255ull * 256 + t] = epv[r] * rdf;
      }
    }
  }
}

extern "C" void kernel_launch(void* const* d_in, const int* in_sizes, int n_in,
                              void* d_out, int out_size, void* d_ws, size_t ws_size,
                              hipStream_t stream) {
  const float* enc  = (const float*)d_in[0];
  const float* h0   = (const float*)d_in[1];
  const float* c0   = (const float*)d_in[2];
  const float* W1   = (const float*)d_in[3];
  const float* W2   = (const float*)d_in[4];
  const float* V    = (const float*)d_in[5];
  const float* Wk   = (const float*)d_in[6];
  const float* Wr   = (const float*)d_in[7];
  const float* bias = (const float*)d_in[8];
  float* out = (float*)d_out;
  float* ws = (float*)d_ws;

  _Float16* w1eh = (_Float16*)(ws + W1EH_OFF);
  float* Wpack   = ws + WPACK_OFF;
  _Float16* W2h  = (_Float16*)(ws + W2H_OFF);
  float* hrowB   = ws + HROW_OFF;
  float* erow    = ws + EROW_OFF;
  float* d2      = ws + D2_OFF;
  unsigned* cnt  = (unsigned*)(ws + CNT_OFF);

  pack_kernel<<<256, 256, 0, stream>>>(Wk, Wr, W2, Wpack, W2h, cnt);
  w1e_kernel<<<dim3(512, 8), 256, 0, stream>>>(enc, W1, w1eh);
  decoder_persistent<<<256, 1024, 0, stream>>>(w1eh, Wpack, W2h, V, bias, h0, c0,
                                               hrowB, erow, d2, cnt, out);
}